// Round 1
// baseline (1930.525 us; speedup 1.0000x reference)
//
#include <hip/hip_runtime.h>

#define TSTEPS 1000
#define BATCH  512
#define HID    64
#define INP    64
#define FEAT   128
#define KEEP   5
#define KH     320        // KEEP*HID
#define ALPHA  0.2f
#define BB     2          // batch per block
#define NBLK   (BATCH/BB) // 256
#define NTHR   512

// workspace layout (float offsets)
#define WS_W1T  0                       // [320][128]
#define WS_W2T  (KH*FEAT)               // [128][64]
#define WS_WHHT (WS_W2T + FEAT*HID)     // [64][64]
#define WS_WINT (WS_WHHT + HID*HID)     // [64][64]

// ---------------- transpose weights into ws ----------------
__global__ void trans_kernel(const float* __restrict__ W_in, const float* __restrict__ W_hh,
                             const float* __restrict__ W1,   const float* __restrict__ W2,
                             float* __restrict__ ws) {
  int idx0 = blockIdx.x * blockDim.x + threadIdx.x;
  int stride = gridDim.x * blockDim.x;
  float* w1t  = ws + WS_W1T;
  float* w2t  = ws + WS_W2T;
  float* whht = ws + WS_WHHT;
  float* wint = ws + WS_WINT;
  for (int i = idx0; i < KH*FEAT; i += stride)  { int j = i >> 7, f = i & 127; w1t[i]  = W1[f*KH + j]; }
  for (int i = idx0; i < FEAT*HID; i += stride) { int f = i >> 6, h = i & 63;  w2t[i]  = W2[h*FEAT + f]; }
  for (int i = idx0; i < HID*HID; i += stride)  { int j = i >> 6, h = i & 63;  whht[i] = W_hh[h*HID + j]; }
  for (int i = idx0; i < INP*HID; i += stride)  { int ii = i >> 6, h = i & 63; wint[i] = W_in[h*INP + ii]; }
}

// ---------------- xin = x @ W_in^T + b_in + b_hh, written into out[t,b,h] ----------------
// weight-stationary: each lane holds W_inT[:, lane] in 64 VGPRs; one wave per (t,b).
__global__ __launch_bounds__(512) void xin_kernel(const float* __restrict__ x,
                                                  const float* __restrict__ ws,
                                                  const float* __restrict__ b_in,
                                                  const float* __restrict__ b_hh,
                                                  float* __restrict__ xin) {
  const float* wint = ws + WS_WINT;
  const int lane = threadIdx.x & 63;
  float wreg[64];
#pragma unroll
  for (int i = 0; i < 64; ++i) wreg[i] = wint[i*HID + lane];
  const float bias = b_in[lane] + b_hh[lane];
  int wid = blockIdx.x * (blockDim.x >> 6) + (threadIdx.x >> 6);
  const int nw = gridDim.x * (blockDim.x >> 6);
  for (int tb = wid; tb < TSTEPS*BATCH; tb += nw) {
    const float* xp = x + (size_t)tb * INP;
    float acc = bias;
#pragma unroll
    for (int i = 0; i < INP; i += 4) {
      float4 xv = *(const float4*)(xp + i);
      acc = fmaf(xv.x, wreg[i+0], acc);
      acc = fmaf(xv.y, wreg[i+1], acc);
      acc = fmaf(xv.z, wreg[i+2], acc);
      acc = fmaf(xv.w, wreg[i+3], acc);
    }
    xin[(size_t)tb * HID + lane] = acc;
  }
}

// ---------------- persistent sequential kernel ----------------
// One block per 2 batch elements. LDS: W1T rows [0,CACHED) cached; rest streamed from L2.
// Per step: A) rnn partials + mlp1 partials (both read only state from step start)
//           B) finalize a=relu(...), h_obs (kept in register by waves 4-5)
//           C) mlp2 partials   D) combine, write out, update h/buf ring.
template<int CACHED>
__global__ __launch_bounds__(512, 1) void seq_kernel(float* __restrict__ io,   // d_out: xin in, h_t out
                                                     const float* __restrict__ h0,
                                                     const float* __restrict__ ws,
                                                     const float* __restrict__ b1,
                                                     const float* __restrict__ b2) {
  const float* w1t  = ws + WS_W1T;
  const float* w2t  = ws + WS_W2T;
  const float* whhg = ws + WS_WHHT;

  extern __shared__ float s[];
  float* w1c  = s;                    // CACHED*128
  float* whh  = s + CACHED*128;       // 4096   W_hhT[j][h]
  float* pA   = whh + 4096;           // 2048   mlp1 partials [8w][2b][128f]
  float* pR   = pA + 2048;            // 1024   rnn partials [8w][2b][64h]; reused as pB for mlp2
  float* bufT = pR + 1024;            // 640    ring [5][64j][2b]
  float* h_t  = bufT + 640;           // 128    h[64j][2b]
  float* a_t  = h_t + 128;            // 256    a[128f][2b]

  const int tid  = threadIdx.x;
  const int w    = (tid >> 6) & 7;
  const int lane = tid & 63;
  const int b0   = blockIdx.x * BB;
  const int jo   = lane >> 5;         // mlp1: row parity
  const int fq   = lane & 31;         // mlp1: float4 column
  const int fb_b = (tid >> 6) & 1;    // finalize threads (256..383): batch
  const int fb_h = lane;              // finalize threads: h index

  // ---- setup ----
  for (int i = tid; i < CACHED*128/4; i += NTHR) ((float4*)w1c)[i] = ((const float4*)w1t)[i];
  for (int i = tid; i < 4096/4; i += NTHR)       ((float4*)whh)[i] = ((const float4*)whhg)[i];
  if (tid < 128) { int b = tid & 1, j = tid >> 1; h_t[j*2 + b] = h0[(b0 + b)*HID + j]; }
  for (int i = tid; i < 640; i += NTHR) bufT[i] = 0.f;
  __syncthreads();

  float hobs_reg = 0.f;

  for (int t = 0; t < TSTEPS; ++t) {
    const int base = t % KEEP;   // invariant: bufT slot (t+k)%5 holds h_{t-5+k}

    // hoist xin load (consumed in phase B by waves 4,5) to overlap with phase A
    float xin_v = 0.f;
    if (tid >= 256 && tid < 384)
      xin_v = io[t*(BATCH*HID) + (b0 + fb_b)*HID + fb_h];

    // ---- phase A1: rnn partials. wave w covers j in [8w, 8w+8), lane = h ----
    {
      float a0 = 0.f, a1 = 0.f;
#pragma unroll
      for (int jj = 0; jj < 8; ++jj) {
        int j = 8*w + jj;
        float wv = whh[j*64 + lane];
        float2 hv = *(const float2*)(h_t + j*2);
        a0 = fmaf(wv, hv.x, a0);
        a1 = fmaf(wv, hv.y, a1);
      }
      pR[(w*2+0)*64 + lane] = a0;
      pR[(w*2+1)*64 + lane] = a1;
    }

    // ---- phase A2: mlp1 partials. wave w covers j in {64k + 8w + 0..7}, k=0..4 ----
    {
      float ax0=0.f, ax1=0.f, ax2=0.f, ax3=0.f;
      float ay0=0.f, ay1=0.f, ay2=0.f, ay3=0.f;
#pragma unroll
      for (int k = 0; k < KEEP; ++k) {
        int sk = base + k; if (sk >= KEEP) sk -= KEEP;
        const float* bufk = bufT + sk*(HID*BB);
#pragma unroll
        for (int ss = 0; ss < 4; ++ss) {
          const int j2 = 64*k + 8*w + 2*ss;   // wave-uniform, even
          const int j  = j2 + jo;
          const int jj = j & 63;
          const float2 bv = *(const float2*)(bufk + jj*2);
          float4 wv;
          if (j2 + 1 < CACHED) wv = *(const float4*)(w1c + (j << 7) + (fq << 2));
          else                 wv = *(const float4*)(w1t + (j << 7) + (fq << 2));
          ax0 = fmaf(wv.x, bv.x, ax0); ax1 = fmaf(wv.y, bv.x, ax1);
          ax2 = fmaf(wv.z, bv.x, ax2); ax3 = fmaf(wv.w, bv.x, ax3);
          ay0 = fmaf(wv.x, bv.y, ay0); ay1 = fmaf(wv.y, bv.y, ay1);
          ay2 = fmaf(wv.z, bv.y, ay2); ay3 = fmaf(wv.w, bv.y, ay3);
        }
      }
      // fold the two row-parities (lanes l and l+32 share (w,b,f))
      ax0 += __shfl_xor(ax0, 32); ax1 += __shfl_xor(ax1, 32);
      ax2 += __shfl_xor(ax2, 32); ax3 += __shfl_xor(ax3, 32);
      ay0 += __shfl_xor(ay0, 32); ay1 += __shfl_xor(ay1, 32);
      ay2 += __shfl_xor(ay2, 32); ay3 += __shfl_xor(ay3, 32);
      if (jo == 0) {
        float4 v0 = make_float4(ax0, ax1, ax2, ax3);
        float4 v1 = make_float4(ay0, ay1, ay2, ay3);
        *(float4*)(pA + ((w*2+0) << 7) + (fq << 2)) = v0;
        *(float4*)(pA + ((w*2+1) << 7) + (fq << 2)) = v1;
      }
    }
    __syncthreads();

    // ---- phase B: finalize a (threads 0..255) and h_obs (threads 256..383) ----
    if (tid < 256) {
      const int b = tid >> 7, f = tid & 127;
      float acc = b1[f];
#pragma unroll
      for (int ww = 0; ww < 8; ++ww) acc += pA[(ww*2+b)*128 + f];
      a_t[f*2 + b] = acc > 0.f ? acc : 0.f;
    } else if (tid < 384) {
      float acc = xin_v;
#pragma unroll
      for (int ww = 0; ww < 8; ++ww) acc += pR[(ww*2+fb_b)*64 + fb_h];
      acc = acc > 0.f ? acc : 0.f;
      hobs_reg = fmaf(h_t[fb_h*2 + fb_b], 1.f - ALPHA, acc * ALPHA);
    }
    __syncthreads();

    // ---- phase C: mlp2 partials. wave w covers f in [16w,16w+16), lane = h ----
    {
      float a0 = 0.f, a1 = 0.f;
#pragma unroll
      for (int ff = 0; ff < 16; ++ff) {
        int f = 16*w + ff;
        float wv = w2t[f*64 + lane];           // global, L1-resident (32 KB)
        float2 av = *(const float2*)(a_t + f*2);
        a0 = fmaf(wv, av.x, a0);
        a1 = fmaf(wv, av.y, a1);
      }
      pR[(w*2+0)*64 + lane] = a0;   // pR safe to reuse: consumed in phase B
      pR[(w*2+1)*64 + lane] = a1;
    }
    __syncthreads();

    // ---- phase D: combine, write out, update state ----
    if (tid >= 256 && tid < 384) {
      float m = b2[fb_h];
#pragma unroll
      for (int ww = 0; ww < 8; ++ww) m += pR[(ww*2+fb_b)*64 + fb_h];
      float hn = (t >= KEEP) ? 0.5f*(hobs_reg + m) : hobs_reg;
      h_t[fb_h*2 + fb_b] = hn;
      bufT[base*(HID*BB) + fb_h*2 + fb_b] = hn;   // overwrite oldest slot
      int o = t*(BATCH*HID) + (b0 + fb_b)*HID + fb_h;
      io[o] = hn;
      if (t == TSTEPS-1) io[TSTEPS*(BATCH*HID) + (b0 + fb_b)*HID + fb_h] = hn;
    }
    __syncthreads();
  }
}

extern "C" void kernel_launch(void* const* d_in, const int* in_sizes, int n_in,
                              void* d_out, int out_size, void* d_ws, size_t ws_size,
                              hipStream_t stream) {
  (void)in_sizes; (void)n_in; (void)out_size; (void)ws_size;
  const float* x    = (const float*)d_in[0];
  const float* h0   = (const float*)d_in[1];
  const float* W_in = (const float*)d_in[2];
  const float* b_in = (const float*)d_in[3];
  const float* W_hh = (const float*)d_in[4];
  const float* b_hh = (const float*)d_in[5];
  const float* W1   = (const float*)d_in[6];
  const float* b1   = (const float*)d_in[7];
  const float* W2   = (const float*)d_in[8];
  const float* b2   = (const float*)d_in[9];
  float* out = (float*)d_out;
  float* ws  = (float*)d_ws;

  trans_kernel<<<64, 256, 0, stream>>>(W_in, W_hh, W1, W2, ws);
  xin_kernel<<<2048, 512, 0, stream>>>(x, ws, b_in, b_hh, out);

  // 248 cached W1T rows -> 159,744 B LDS (needs opt-in); fallback = 64 rows (65,536 B)
  const int lds_big = 248*512 + 32768;
  hipError_t rc = hipFuncSetAttribute(reinterpret_cast<const void*>(&seq_kernel<248>),
                                      hipFuncAttributeMaxDynamicSharedMemorySize, lds_big);
  if (rc == hipSuccess) {
    seq_kernel<248><<<NBLK, NTHR, lds_big, stream>>>(out, h0, ws, b1, b2);
  } else {
    seq_kernel<64><<<NBLK, NTHR, 64*512 + 32768, stream>>>(out, h0, ws, b1, b2);
  }
}

// Round 2
// 1725.946 us; speedup vs baseline: 1.1185x; 1.1185x over previous
//
#include <hip/hip_runtime.h>

#define TSTEPS 1000
#define BATCH  512
#define HID    64
#define INP    64
#define FEAT   128
#define KEEP   5
#define KH     320        // KEEP*HID
#define ALPHA  0.2f
#define BB     2          // batch per block
#define NBLK   (BATCH/BB) // 256
#define NTHR   512

// broadcast lane l's value to all lanes via SGPR (VALU slot, not LDS pipe)
__device__ __forceinline__ float rdlane(float v, int l) {
  return __int_as_float(__builtin_amdgcn_readlane(__float_as_int(v), l));
}

// ---------------- xin = x @ W_in^T + b_in + b_hh, written into out[t,b,h] ----------------
__global__ __launch_bounds__(512) void xin_kernel(const float* __restrict__ x,
                                                  const float* __restrict__ W_in,
                                                  const float* __restrict__ b_in,
                                                  const float* __restrict__ b_hh,
                                                  float* __restrict__ xin) {
  const int lane = threadIdx.x & 63;
  float wreg[64];
  const float4* wrow = (const float4*)(W_in + lane * INP);  // W_in[h=lane][i] contiguous
#pragma unroll
  for (int q = 0; q < 16; ++q) {
    float4 v = wrow[q];
    wreg[4*q+0] = v.x; wreg[4*q+1] = v.y; wreg[4*q+2] = v.z; wreg[4*q+3] = v.w;
  }
  const float bias = b_in[lane] + b_hh[lane];
  int wid = blockIdx.x * (blockDim.x >> 6) + (threadIdx.x >> 6);
  const int nw = gridDim.x * (blockDim.x >> 6);
  for (int tb = wid; tb < TSTEPS*BATCH; tb += nw) {
    const float* xp = x + (size_t)tb * INP;
    float acc = bias;
#pragma unroll
    for (int i = 0; i < INP; i += 4) {
      float4 xv = *(const float4*)(xp + i);
      acc = fmaf(xv.x, wreg[i+0], acc);
      acc = fmaf(xv.y, wreg[i+1], acc);
      acc = fmaf(xv.z, wreg[i+2], acc);
      acc = fmaf(xv.w, wreg[i+3], acc);
    }
    xin[(size_t)tb * HID + lane] = acc;
  }
}

// ---------------- persistent sequential kernel: weights in VGPRs ----------------
// 512 thr = 8 waves, BB=2 batch/block, 256 blocks (1/CU).
// wave w: MLP1 j-window [40w,40w+40), lane owns f={lane,lane+64}  -> 80 W1 regs
//         RNN  j-window [8w,8w+8),    lane owns h=lane            -> 8 W_hh regs
//         MLP2 f-window [16w,16w+16), lane owns h=lane            -> 16 W2 regs
// Per step: A) MLP1+RNN partials -> pA,pR | bar | C) reduce a-slice + MLP2 -> pR2 | bar
//           D) waves 0,1 combine + write | bar.   Broadcasts via readlane (no LDS).
__global__ __launch_bounds__(NTHR, 2) void seq_kernel(float* __restrict__ io,
                                                      const float* __restrict__ h0,
                                                      const float* __restrict__ W_hh,
                                                      const float* __restrict__ W1,
                                                      const float* __restrict__ b1g,
                                                      const float* __restrict__ W2,
                                                      const float* __restrict__ b2g) {
  __shared__ float pA[8*128*2];     // [w][f][b] mlp1 partials
  __shared__ float pR[8*64*2];      // [w][h][b] rnn partials
  __shared__ float pR2[8*64*2];     // [w][h][b] mlp2 partials
  __shared__ float bufT[KEEP*64*2]; // [slot][j][b] hidden ring
  __shared__ float h_s[64*2];       // [j][b]

  const int tid  = threadIdx.x;
  const int w    = tid >> 6;
  const int lane = tid & 63;
  const int b0   = blockIdx.x * BB;

  // ---- weight registers (one-time global reads; weights are L2-resident) ----
  float w1a[40], w1b[40];
  {
    const float* ra = W1 + (size_t)lane * KH + 40*w;        // W1[f=lane][j]
    const float* rb = W1 + (size_t)(lane+64) * KH + 40*w;   // W1[f=lane+64][j]
#pragma unroll
    for (int q = 0; q < 10; ++q) {
      float4 va = *(const float4*)(ra + 4*q);
      float4 vb = *(const float4*)(rb + 4*q);
      w1a[4*q+0]=va.x; w1a[4*q+1]=va.y; w1a[4*q+2]=va.z; w1a[4*q+3]=va.w;
      w1b[4*q+0]=vb.x; w1b[4*q+1]=vb.y; w1b[4*q+2]=vb.z; w1b[4*q+3]=vb.w;
    }
  }
  float whr[8];
  {
    const float* rh = W_hh + lane * HID + 8*w;              // W_hh[h=lane][j]
#pragma unroll
    for (int q = 0; q < 2; ++q) {
      float4 v = *(const float4*)(rh + 4*q);
      whr[4*q+0]=v.x; whr[4*q+1]=v.y; whr[4*q+2]=v.z; whr[4*q+3]=v.w;
    }
  }
  float w2r[16];
  {
    const float* r2 = W2 + lane * FEAT + 16*w;              // W2[h=lane][f]
#pragma unroll
    for (int q = 0; q < 4; ++q) {
      float4 v = *(const float4*)(r2 + 4*q);
      w2r[4*q+0]=v.x; w2r[4*q+1]=v.y; w2r[4*q+2]=v.z; w2r[4*q+3]=v.w;
    }
  }
  const float b1v = (lane < 16) ? b1g[16*w + lane] : 0.f;
  const float b2v = b2g[lane];

  // MLP1 window address pieces (constant per thread)
  const int jg   = 40*w + lane;          // valid when lane<40
  const int k_c  = jg >> 6;
  const int jj_c = jg & 63;

  // ---- state init ----
  if (tid < 128) h_s[tid] = h0[(b0 + (tid & 1)) * HID + (tid >> 1)];
  for (int i = tid; i < KEEP*128; i += NTHR) bufT[i] = 0.f;
  __syncthreads();

  int base = 0;  // ring slot holding the oldest entry (== t % KEEP)
  for (int t = 0; t < TSTEPS; ++t) {
    // prefetch this step's xin (consumed in phase D, 2 barriers later)
    float xv = 0.f;
    if (w < 2) xv = io[t*(BATCH*HID) + (b0 + w)*HID + lane];

    // ---- phase A: MLP1 + RNN partials ----
    float2 bv = make_float2(0.f, 0.f);
    if (lane < 40) {
      int slot = base + k_c; if (slot >= KEEP) slot -= KEEP;
      bv = *(const float2*)(bufT + slot*128 + jj_c*2);
    }
    float2 hv = make_float2(0.f, 0.f);
    if (lane < 8) hv = *(const float2*)(h_s + (8*w + lane)*2);

    float a00=0.f, a01=0.f, a10=0.f, a11=0.f;
#pragma unroll
    for (int jj = 0; jj < 40; ++jj) {
      float s0 = rdlane(bv.x, jj);
      float s1 = rdlane(bv.y, jj);
      a00 = fmaf(w1a[jj], s0, a00);
      a01 = fmaf(w1a[jj], s1, a01);
      a10 = fmaf(w1b[jj], s0, a10);
      a11 = fmaf(w1b[jj], s1, a11);
    }
    float r0=0.f, r1=0.f;
#pragma unroll
    for (int jj = 0; jj < 8; ++jj) {
      float s0 = rdlane(hv.x, jj);
      float s1 = rdlane(hv.y, jj);
      r0 = fmaf(whr[jj], s0, r0);
      r1 = fmaf(whr[jj], s1, r1);
    }
    *(float2*)(pA + w*256 + lane*2)         = make_float2(a00, a01);
    *(float2*)(pA + w*256 + 128 + lane*2)   = make_float2(a10, a11);
    *(float2*)(pR + w*128 + lane*2)         = make_float2(r0, r1);
    __syncthreads();

    // ---- phase C: reduce the a-slice this wave consumes, then MLP2 partials ----
    float aR0 = 0.f, aR1 = 0.f;
    if (lane < 16) {
      const int f = 16*w + lane;
      float s0 = b1v, s1 = b1v;
#pragma unroll
      for (int ww = 0; ww < 8; ++ww) {
        float2 p = *(const float2*)(pA + ww*256 + f*2);
        s0 += p.x; s1 += p.y;
      }
      aR0 = fmaxf(s0, 0.f);
      aR1 = fmaxf(s1, 0.f);
    }
    float c0=0.f, c1=0.f;
#pragma unroll
    for (int ff = 0; ff < 16; ++ff) {
      float s0 = rdlane(aR0, ff);
      float s1 = rdlane(aR1, ff);
      c0 = fmaf(w2r[ff], s0, c0);
      c1 = fmaf(w2r[ff], s1, c1);
    }
    *(float2*)(pR2 + w*128 + lane*2) = make_float2(c0, c1);
    __syncthreads();

    // ---- phase D: combine, write out, update state (waves 0,1; b = w) ----
    if (w < 2) {
      const int b = w;
      float sr = 0.f, sm = b2v;
#pragma unroll
      for (int ww = 0; ww < 8; ++ww) {
        sr += pR [ww*128 + lane*2 + b];
        sm += pR2[ww*128 + lane*2 + b];
      }
      float hprev = h_s[lane*2 + b];
      float hobs  = fmaf(hprev, 1.f - ALPHA, fmaxf(xv + sr, 0.f) * ALPHA);
      float hn    = (t >= KEEP) ? 0.5f*(hobs + sm) : hobs;
      h_s[lane*2 + b]          = hn;
      bufT[base*128 + lane*2 + b] = hn;   // overwrite oldest slot
      io[t*(BATCH*HID) + (b0 + b)*HID + lane] = hn;
      if (t == TSTEPS-1) io[TSTEPS*(BATCH*HID) + (b0 + b)*HID + lane] = hn;
    }
    __syncthreads();

    base = (base == KEEP-1) ? 0 : base + 1;
  }
}

extern "C" void kernel_launch(void* const* d_in, const int* in_sizes, int n_in,
                              void* d_out, int out_size, void* d_ws, size_t ws_size,
                              hipStream_t stream) {
  (void)in_sizes; (void)n_in; (void)out_size; (void)d_ws; (void)ws_size;
  const float* x    = (const float*)d_in[0];
  const float* h0   = (const float*)d_in[1];
  const float* W_in = (const float*)d_in[2];
  const float* b_in = (const float*)d_in[3];
  const float* W_hh = (const float*)d_in[4];
  const float* b_hh = (const float*)d_in[5];
  const float* W1   = (const float*)d_in[6];
  const float* b1   = (const float*)d_in[7];
  const float* W2   = (const float*)d_in[8];
  const float* b2   = (const float*)d_in[9];
  float* out = (float*)d_out;

  xin_kernel<<<2048, 512, 0, stream>>>(x, W_in, b_in, b_hh, out);
  seq_kernel<<<NBLK, NTHR, 0, stream>>>(out, h0, W_hh, W1, b1, W2, b2);
}